// Round 5
// baseline (108.566 us; speedup 1.0000x reference)
//
#include <hip/hip_runtime.h>
#include <stdint.h>

#define BATCH 32
#define NBOX 8192
#define NGT 128
#define M (NBOX + NGT)     // 8320
#define K_OUT 512
#define MAX_FG 128
#define C_CAP 256          // kth boundary-bucket members (~npos/1024, Poisson)
#define S_CAP 256          // selp members (<= 128 + value-ties)
#define U_CAP 1024         // neg union (<= k2 + boundary bucket)

#define GSPLIT 2
#define GPER (NGT / GSPLIT)                       // 64 gts per split
#define IOU_TPB 256
#define IOU_CB ((M + IOU_TPB - 1) / IOU_TPB)      // 33 box-chunks

// Monotone clamped bucket: v1>v2 => bkt(v1)>=bkt(v2); bkt(v1)>bkt(v2) => v1>v2.
__device__ __forceinline__ unsigned int bkt1024(float ns) {
    unsigned int u = (unsigned int)(ns * 16777216.0f) >> 14;
    return u > 1023u ? 1023u : u;
}

#define U64KEY(lo, hi) (((unsigned long long)(hi) << 32) | (unsigned long long)(lo))

// ---------------------------------------------------------------------------
// Kernel 1 v5: gt-split grid (2112 blocks = 8 blocks/CU, 32 waves/CU) kept
// from v4. Change: sga (gt area) no longer staged in LDS -- recomputed per
// iter in VALU with the IDENTICAL __fmul_rn/__fsub_rn sequence (bit-exact).
// Rationale: per-CU LDS pipe was the binding resource (b128+b32 = ~18 cyc/
// iter/wave x 32 waves > VALU 50 cyc/4 SIMDs); now one ds_read_b128 only.
// Partial result: order-exact u64 key (bits(best)<<32)|(127-idx); max-merge
// in select = global first-max argmax (best >= 0 so f32 bits uint-monotone;
// tie -> larger 127-idx -> smaller idx). Exact __fdiv_rn kept: rounded-
// quotient ordering is semantically observable.
// ---------------------------------------------------------------------------
__global__ __launch_bounds__(256) void iou_kernel(
    const float* __restrict__ boxes,      // [B, NBOX, 4]
    const float* __restrict__ gt_boxes,   // [B, NGT, 4]
    unsigned long long* __restrict__ part) // [GSPLIT, B, M]
{
    const int s  = blockIdx.x % GSPLIT;
    const int cb = (blockIdx.x / GSPLIT) % IOU_CB;
    const int b  = blockIdx.x / (GSPLIT * IOU_CB);
    const int t  = threadIdx.x;
    const int g0 = s * GPER;

    __shared__ float4 sgt[GPER];
    if (t < GPER)
        sgt[t] = ((const float4*)gt_boxes)[b * NGT + g0 + t];
    __syncthreads();

    const int m = cb * IOU_TPB + t;
    if (m >= M) return;

    float4 bb = (m < NBOX) ? ((const float4*)boxes)[b * NBOX + m]
                           : ((const float4*)gt_boxes)[b * NGT + (m - NBOX)];
    float ba = __fmul_rn(__fsub_rn(bb.z, bb.x), __fsub_rn(bb.w, bb.y));

    float best = -1e30f;
    int bi = 0;
    #pragma unroll 4
    for (int g = 0; g < GPER; ++g) {
        float4 gg = sgt[g];
        float ga = __fmul_rn(__fsub_rn(gg.z, gg.x), __fsub_rn(gg.w, gg.y));
        float iymin = fmaxf(bb.x, gg.x);
        float ixmin = fmaxf(bb.y, gg.y);
        float iymax = fminf(bb.z, gg.z);
        float ixmax = fminf(bb.w, gg.w);
        float ia  = __fmul_rn(fmaxf(__fsub_rn(iymax, iymin), 0.0f),
                              fmaxf(__fsub_rn(ixmax, ixmin), 0.0f));
        float den = __fsub_rn(__fadd_rn(ba, ga), ia);
        float iou = __fdiv_rn(ia, den);
        if (iou > best) { best = iou; bi = g0 + g; }     // first-max = argmax
    }
    // best >= 0 here (first iteration always beats -1e30; iou >= 0).
    part[((size_t)s * BATCH + b) * M + m] =
        U64KEY(127u - (unsigned int)bi, __float_as_uint(best));
}

// Merge the GSPLIT partial keys for one item -> global argmax label.
__device__ __forceinline__ int merged_label(
    const unsigned long long* __restrict__ P0,
    const unsigned long long* __restrict__ P1, int m) {
    unsigned long long ka = P0[m], kb = P1[m];
    unsigned long long kk = ka > kb ? ka : kb;
    return (int)(127u - ((unsigned int)kk & 127u));
}

// ---------------------------------------------------------------------------
// Kernel 2 v5: one block (1024 thr) per batch.
// Changes vs verified v4: (a) sh_idx LDS byte-scatter dropped -- the ~130
// selp winners (and impossible fallback) re-read their own 2 partial u64s
// and re-merge (2 global loads each); (b) pos/neg masks packed into one
// ushort LDS write (lo byte pos, hi byte neg); (c) partials loaded as
// ulonglong2. Rank-bearing logic (histograms, boundary-bucket kth, selp
// pairwise rank, neg positional bucket placement + within-bucket exact
// rank) unchanged -> bit-exact vs jax top_k semantics.
// ---------------------------------------------------------------------------
__global__ __launch_bounds__(1024) void select_kernel(
    const float* __restrict__ boxes,
    const float* __restrict__ gt_boxes,
    const int*   __restrict__ gt_labels,
    const float* __restrict__ noise,      // [B, M]
    const unsigned long long* __restrict__ part,  // [GSPLIT, B, M]
    float* __restrict__ out)
{
    const int b = blockIdx.x;
    const int tid = threadIdx.x;

    __shared__ float sh_ns[M];                 // 33280 B
    __shared__ unsigned int hist[1024];        // neg hist -> suffix counts
    __shared__ unsigned int hist2[1024];       // pos hist -> suffix counts
    __shared__ unsigned int bctr[1024];        // per-bucket placement counters
    __shared__ unsigned short pnmask[M / 8];   // lo byte: pos bits, hi: neg
    __shared__ float4 sgt[NGT];
    __shared__ int slab[NGT];
    __shared__ float C[C_CAP];
    __shared__ __align__(16) unsigned int   skey[S_CAP + 4];
    __shared__ __align__(16) unsigned short sm[S_CAP + 4];
    __shared__ unsigned int   ukey[U_CAP];
    __shared__ unsigned short um[U_CAP];
    __shared__ unsigned int sh_Bp, sh_needp, sh_cc, sh_n1a, sh_B, sh_kth;

    float* out_bt  = out;
    float* out_cls = out + BATCH * K_OUT * 4;
    float* out_roi = out + BATCH * K_OUT * 5;
    float* out_p2l = out + BATCH * K_OUT * 9;

    const unsigned long long* P0 = part + ((size_t)0 * BATCH + b) * M;
    const unsigned long long* P1 = part + ((size_t)1 * BATCH + b) * M;

    // ---- init + stage gt ---------------------------------------------------
    hist[tid] = 0;
    hist2[tid] = 0;
    bctr[tid] = 0;
    if (tid == 0) { sh_cc = 0; sh_n1a = 0; sh_B = 0; sh_kth = 0xBF800000u; }
    if (tid < NGT) {
        sgt[tid]  = ((const float4*)gt_boxes)[b * NGT + tid];
        slab[tid] = gt_labels[b * NGT + tid];
    }
    __syncthreads();

    // ---- load pass: merge split keys, noise -> LDS + regs, masks + hists ---
    float f[8];                                // this thread's chunk (c = tid)
    unsigned int pb = 0, nb = 0;
    {
        const float4* ns4 = (const float4*)(noise + (size_t)b * M);
        {
            const int c = tid;
            const ulonglong2* a2 = (const ulonglong2*)(P0 + (size_t)c * 8);
            const ulonglong2* b2 = (const ulonglong2*)(P1 + (size_t)c * 8);
            ulonglong2 A0 = a2[0], A1 = a2[1], A2 = a2[2], A3 = a2[3];
            ulonglong2 B0 = b2[0], B1 = b2[1], B2 = b2[2], B3 = b2[3];
            float4 n0 = ns4[2 * c], n1v = ns4[2 * c + 1];
            ((float4*)sh_ns)[2 * c] = n0;
            ((float4*)sh_ns)[2 * c + 1] = n1v;
            f[0] = n0.x; f[1] = n0.y; f[2] = n0.z; f[3] = n0.w;
            f[4] = n1v.x; f[5] = n1v.y; f[6] = n1v.z; f[7] = n1v.w;
            unsigned long long ka[8] = {A0.x, A0.y, A1.x, A1.y,
                                        A2.x, A2.y, A3.x, A3.y};
            unsigned long long kb[8] = {B0.x, B0.y, B1.x, B1.y,
                                        B2.x, B2.y, B3.x, B3.y};
            #pragma unroll
            for (int k = 0; k < 8; ++k) {
                unsigned long long kk = ka[k] > kb[k] ? ka[k] : kb[k];
                unsigned int ub = (unsigned int)(kk >> 32);
                if (ub > 0x3F000000u) {             // best > 0.5f
                    pb |= (1u << k);
                    atomicAdd(&hist2[bkt1024(f[k])], 1u);
                } else if (ub < 0x3F000000u) {      // best < 0.5f (best >= 0)
                    nb |= (1u << k);
                    atomicAdd(&hist[bkt1024(f[k])], 1u);
                }
            }
            pnmask[c] = (unsigned short)(pb | (nb << 8));
        }
        if (tid < 16) {                            // tail chunks 1024..1039
            const int c = 1024 + tid;
            const ulonglong2* a2 = (const ulonglong2*)(P0 + (size_t)c * 8);
            const ulonglong2* b2 = (const ulonglong2*)(P1 + (size_t)c * 8);
            ulonglong2 A0 = a2[0], A1 = a2[1], A2 = a2[2], A3 = a2[3];
            ulonglong2 B0 = b2[0], B1 = b2[1], B2 = b2[2], B3 = b2[3];
            float4 n0 = ns4[2 * c], n1v = ns4[2 * c + 1];
            ((float4*)sh_ns)[2 * c] = n0;
            ((float4*)sh_ns)[2 * c + 1] = n1v;
            float ft[8] = {n0.x, n0.y, n0.z, n0.w, n1v.x, n1v.y, n1v.z, n1v.w};
            unsigned long long ka[8] = {A0.x, A0.y, A1.x, A1.y,
                                        A2.x, A2.y, A3.x, A3.y};
            unsigned long long kb[8] = {B0.x, B0.y, B1.x, B1.y,
                                        B2.x, B2.y, B3.x, B3.y};
            unsigned int pb2 = 0, nb2 = 0;
            #pragma unroll
            for (int k = 0; k < 8; ++k) {
                unsigned long long kk = ka[k] > kb[k] ? ka[k] : kb[k];
                unsigned int ub = (unsigned int)(kk >> 32);
                if (ub > 0x3F000000u) {
                    pb2 |= (1u << k);
                    atomicAdd(&hist2[bkt1024(ft[k])], 1u);
                } else if (ub < 0x3F000000u) {
                    nb2 |= (1u << k);
                    atomicAdd(&hist[bkt1024(ft[k])], 1u);
                }
            }
            pnmask[c] = (unsigned short)(pb2 | (nb2 << 8));
        }
    }
    __syncthreads();

    // ---- suffix scans: wave 0 -> hist (neg), wave 1 -> hist2 (pos) ---------
    {
        const int wv = tid >> 6, ln = tid & 63;
        if (wv < 2) {
            unsigned int* H = wv ? hist2 : hist;
            unsigned int s[16];
            #pragma unroll
            for (int k = 0; k < 16; ++k) {
                unsigned int v = H[k * 64 + ln];
                #pragma unroll
                for (int off = 1; off < 64; off <<= 1) {
                    unsigned int o = __shfl_down(v, off, 64);
                    if (ln + off < 64) v += o;
                }
                s[k] = v;
            }
            unsigned int after = 0;
            #pragma unroll
            for (int k = 15; k >= 0; --k) {
                unsigned int tot = __shfl(s[k], 0, 64);
                H[k * 64 + ln] = s[k] + after;
                after += tot;
            }
        }
    }
    __syncthreads();
    const unsigned int nneg = hist[0];
    const unsigned int npos = hist2[0];

    // ---- kth = 128th-largest pos noise (capacity-free, exact) --------------
    if (npos >= MAX_FG) {                       // block-uniform branch
        {
            unsigned int S  = hist2[tid];
            unsigned int Sn = (tid < 1023) ? hist2[tid + 1] : 0;
            if (S >= MAX_FG && Sn < MAX_FG) { sh_Bp = tid; sh_needp = MAX_FG - Sn; }
        }
        __syncthreads();
        const unsigned int Bp = sh_Bp, needp = sh_needp;
        #pragma unroll
        for (int k = 0; k < 8; ++k) {
            if (((pb >> k) & 1u) && bkt1024(f[k]) == Bp) {
                unsigned int slot = atomicAdd(&sh_cc, 1u);
                if (slot < C_CAP) C[slot] = f[k];
            }
        }
        if (tid < 16) {
            unsigned int pb2 = pnmask[1024 + tid] & 0xFFu;
            #pragma unroll
            for (int k = 0; k < 8; ++k) {
                if ((pb2 >> k) & 1u) {
                    float v = sh_ns[(1024 + tid) * 8 + k];
                    if (bkt1024(v) == Bp) {
                        unsigned int slot = atomicAdd(&sh_cc, 1u);
                        if (slot < C_CAP) C[slot] = v;
                    }
                }
            }
        }
        __syncthreads();
        {   // exact in-bucket value rank: v with #greater < needp <= #greater+#eq
            unsigned int cc = min(sh_cc, (unsigned int)C_CAP);
            if (tid < (int)cc) {
                float my = C[tid];
                unsigned int g = 0, e = 0;
                for (unsigned int j = 0; j < cc; ++j) {
                    float v = C[j];
                    g += (v > my) ? 1u : 0u;
                    e += (v == my) ? 1u : 0u;
                }
                if (g < needp && g + e >= needp) sh_kth = __float_as_uint(my);
            }
        }
        __syncthreads();
    }
    const float kthf = __uint_as_float(sh_kth);

    // ---- selp collection: pos && ns >= kth; store key = bits(2+ns) ---------
    #pragma unroll
    for (int k = 0; k < 8; ++k) {
        if (((pb >> k) & 1u) && f[k] >= kthf) {
            unsigned int slot = atomicAdd(&sh_n1a, 1u);
            if (slot < S_CAP) {
                skey[slot] = __float_as_uint(__fadd_rn(2.0f, f[k]));
                sm[slot]   = (unsigned short)(tid * 8 + k);
            }
        }
    }
    if (tid < 16) {
        unsigned int pb2 = pnmask[1024 + tid] & 0xFFu;
        #pragma unroll
        for (int k = 0; k < 8; ++k) {
            if ((pb2 >> k) & 1u) {
                int m = (1024 + tid) * 8 + k;
                float v = sh_ns[m];
                if (v >= kthf) {
                    unsigned int slot = atomicAdd(&sh_n1a, 1u);
                    if (slot < S_CAP) {
                        skey[slot] = __float_as_uint(__fadd_rn(2.0f, v));
                        sm[slot]   = (unsigned short)m;
                    }
                }
            }
        }
    }
    __syncthreads();
    const unsigned int n1 = min(sh_n1a, (unsigned int)S_CAP);
    const unsigned int k2 = K_OUT - n1;         // >= 382 expected
    const bool enough_neg = (nneg >= k2);

    if (tid < 4) { skey[n1 + tid] = 0u; sm[n1 + tid] = 0xFFFFu; }  // pad
    if (enough_neg) {
        unsigned int S  = hist[tid];
        unsigned int Sn = (tid < 1023) ? hist[tid + 1] : 0;
        if (S >= k2 && Sn < k2) sh_B = tid;     // unique writer
    }   // else sh_B stays 0 -> place all negs
    __syncthreads();
    const unsigned int B1 = sh_B;

    // ---- selp exact pairwise rank (vectorized LDS reads) + fg writes -------
    if (tid < (int)n1) {
        unsigned int   ki = skey[tid];
        unsigned short mi = sm[tid];
        unsigned int r = 0;
        for (unsigned int j = 0; j < n1; j += 4) {
            uint4   kv = *(const uint4*)&skey[j];
            ushort4 mv = *(const ushort4*)&sm[j];
            r += (kv.x > ki || (kv.x == ki && mv.x < mi)) ? 1u : 0u;
            r += (kv.y > ki || (kv.y == ki && mv.y < mi)) ? 1u : 0u;
            r += (kv.z > ki || (kv.z == ki && mv.z < mi)) ? 1u : 0u;
            r += (kv.w > ki || (kv.w == ki && mv.w < mi)) ? 1u : 0u;
        }
        int mi_ = mi;
        int lbl = merged_label(P0, P1, mi_);
        float4 roi = (mi_ < NBOX) ? ((const float4*)boxes)[b * NBOX + mi_]
                                  : sgt[mi_ - NBOX];
        ((float4*)out_bt)[b * K_OUT + r] = sgt[lbl];
        out_cls[b * K_OUT + r] = (float)slab[lbl];
        ((float4*)out_roi)[b * K_OUT + r] = roi;
        out_p2l[b * K_OUT + r] = (float)lbl;
    }

    // ---- neg bucket placement: positional, rank-exact ----------------------
    #pragma unroll
    for (int k = 0; k < 8; ++k) {
        if ((nb >> k) & 1u) {
            float v = f[k];
            unsigned int be = bkt1024(v);
            if (be >= B1) {
                unsigned int base = (be < 1023) ? hist[be + 1] : 0;
                unsigned int a = base + atomicAdd(&bctr[be], 1u);
                if (a < U_CAP) {
                    ukey[a] = __float_as_uint(v);   // v >= 0: uint-monotone
                    um[a]   = (unsigned short)(tid * 8 + k);
                }
            }
        }
    }
    if (tid < 16) {
        unsigned int nb2 = (pnmask[1024 + tid] >> 8) & 0xFFu;
        #pragma unroll
        for (int k = 0; k < 8; ++k) {
            if ((nb2 >> k) & 1u) {
                int m = (1024 + tid) * 8 + k;
                float v = sh_ns[m];
                unsigned int be = bkt1024(v);
                if (be >= B1) {
                    unsigned int base = (be < 1023) ? hist[be + 1] : 0;
                    unsigned int a = base + atomicAdd(&bctr[be], 1u);
                    if (a < U_CAP) {
                        ukey[a] = __float_as_uint(v);
                        um[a]   = (unsigned short)m;
                    }
                }
            }
        }
    }
    __syncthreads();

    // ---- neg finalize: within-bucket exact rank over own segment -----------
    const unsigned int q = min(hist[B1], (unsigned int)U_CAP);
    for (unsigned int a = tid; a < q; a += 1024) {
        unsigned int   ki = ukey[a];
        unsigned short mi = um[a];
        unsigned int be = bkt1024(__uint_as_float(ki));
        unsigned int base = (be < 1023) ? hist[be + 1] : 0;
        unsigned int end  = min(hist[be], q);
        unsigned int r = base;
        for (unsigned int j = base; j < end; ++j) {
            unsigned int kj = ukey[j];
            if (kj > ki || (kj == ki && um[j] < mi)) ++r;
        }
        if (r < k2) {
            float4 roi = (mi < NBOX) ? ((const float4*)boxes)[b * NBOX + mi]
                                     : sgt[mi - NBOX];
            unsigned int gr = n1 + r;
            ((float4*)out_bt)[b * K_OUT + gr] = make_float4(0.f, 0.f, 0.f, 0.f);
            out_cls[b * K_OUT + gr] = 0.0f;
            ((float4*)out_roi)[b * K_OUT + gr] = roi;
            out_p2l[b * K_OUT + gr] = 0.0f;
        }
    }

    // ---- fallback (statistically impossible: nneg < k2): rest by m asc -----
    if (!enough_neg) {
        __syncthreads();
        const unsigned int k3 = k2 - nneg;
        for (int m = tid; m < M; m += 1024) {
            if (((pnmask[m >> 3] >> (m & 7)) & 1) && sh_ns[m] < kthf) {
                unsigned int r = 0;
                for (int m2 = 0; m2 < m; ++m2)
                    if (((pnmask[m2 >> 3] >> (m2 & 7)) & 1) && sh_ns[m2] < kthf) ++r;
                if (r < k3) {
                    int lbl = merged_label(P0, P1, m);
                    float4 roi = (m < NBOX) ? ((const float4*)boxes)[b * NBOX + m]
                                            : sgt[m - NBOX];
                    unsigned int gr = n1 + nneg + r;
                    ((float4*)out_bt)[b * K_OUT + gr] = sgt[lbl];
                    out_cls[b * K_OUT + gr] = (float)slab[lbl];
                    ((float4*)out_roi)[b * K_OUT + gr] = roi;
                    out_p2l[b * K_OUT + gr] = (float)lbl;
                }
            }
        }
    }
}

extern "C" void kernel_launch(void* const* d_in, const int* in_sizes, int n_in,
                              void* d_out, int out_size, void* d_ws, size_t ws_size,
                              hipStream_t stream) {
    const float* boxes     = (const float*)d_in[0];
    const float* gt_boxes  = (const float*)d_in[1];
    const int*   gt_labels = (const int*)d_in[2];
    const float* noise     = (const float*)d_in[3];
    unsigned long long* part = (unsigned long long*)d_ws;  // GSPLIT*B*M u64 = 4.26 MB
    float* out = (float*)d_out;

    iou_kernel<<<BATCH * IOU_CB * GSPLIT, IOU_TPB, 0, stream>>>(boxes, gt_boxes, part);
    select_kernel<<<BATCH, 1024, 0, stream>>>(boxes, gt_boxes, gt_labels, noise,
                                              part, out);
}